// Round 8
// baseline (284.459 us; speedup 1.0000x reference)
//
#include <hip/hip_runtime.h>

#define TT 512
#define FF 8
#define CC 16
#define HH 10
#define G4 40

__device__ __forceinline__ float rl(float v, int k){
    return __int_as_float(__builtin_amdgcn_readlane(__float_as_int(v), k));
}
__device__ __forceinline__ float sigf(float z){
    return __builtin_amdgcn_rcpf(1.f + __expf(-z));
}
__device__ __forceinline__ float tanh_f(float z){
    return 1.f - 2.f * __builtin_amdgcn_rcpf(1.f + __expf(2.f * z));
}
// Pin a value into a VGPR: asm output is opaque -> compiler must keep it live
// (cannot rematerialize from memory).
#define PIN(v) asm volatile("" : "+v"(v))

#define CONV_Y(Y) do{                                                                              \
    float a0 = cb, a1 = 0.f;                                                                       \
    a0 = fmaf(w0a.x, cw0,  a0); a1 = fmaf(w1a.x, cw1,  a1); a0 = fmaf(w2a.x, cw2,  a0);            \
    a1 = fmaf(w0a.y, cw3,  a1); a0 = fmaf(w1a.y, cw4,  a0); a1 = fmaf(w2a.y, cw5,  a1);            \
    a0 = fmaf(w0a.z, cw6,  a0); a1 = fmaf(w1a.z, cw7,  a1); a0 = fmaf(w2a.z, cw8,  a0);            \
    a1 = fmaf(w0a.w, cw9,  a1); a0 = fmaf(w1a.w, cw10, a0); a1 = fmaf(w2a.w, cw11, a1);            \
    a0 = fmaf(w0b.x, cw12, a0); a1 = fmaf(w1b.x, cw13, a1); a0 = fmaf(w2b.x, cw14, a0);            \
    a1 = fmaf(w0b.y, cw15, a1); a0 = fmaf(w1b.y, cw16, a0); a1 = fmaf(w2b.y, cw17, a1);            \
    a0 = fmaf(w0b.z, cw18, a0); a1 = fmaf(w1b.z, cw19, a1); a0 = fmaf(w2b.z, cw20, a0);            \
    a1 = fmaf(w0b.w, cw21, a1); a0 = fmaf(w1b.w, cw22, a0); a1 = fmaf(w2b.w, cw23, a1);            \
    Y = fmaxf(a0 + a1, 0.f);                                                                       \
}while(0)

#define H1BCAST                                                                                    \
    const float hs0=rl(h1,0), hs1=rl(h1,1), hs2=rl(h1,2), hs3=rl(h1,3), hs4=rl(h1,4),              \
                hs5=rl(h1,5), hs6=rl(h1,6), hs7=rl(h1,7), hs8=rl(h1,8), hs9=rl(h1,9);

#define LAYER2 do{                                                                                 \
    float d0 = b2, d1 = 0.f;                                                                       \
    d0 = fmaf(hs0, wi2_0, d0);  d1 = fmaf(hs1, wi2_1, d1);                                         \
    d0 = fmaf(hs2, wi2_2, d0);  d1 = fmaf(hs3, wi2_3, d1);                                         \
    d0 = fmaf(hs4, wi2_4, d0);  d1 = fmaf(hs5, wi2_5, d1);                                         \
    d0 = fmaf(hs6, wi2_6, d0);  d1 = fmaf(hs7, wi2_7, d1);                                         \
    d0 = fmaf(hs8, wi2_8, d0);  d1 = fmaf(hs9, wi2_9, d1);                                         \
    d0 = fmaf(rl(h2,0), wh2_0, d0);  d1 = fmaf(rl(h2,1), wh2_1, d1);                               \
    d0 = fmaf(rl(h2,2), wh2_2, d0);  d1 = fmaf(rl(h2,3), wh2_3, d1);                               \
    d0 = fmaf(rl(h2,4), wh2_4, d0);  d1 = fmaf(rl(h2,5), wh2_5, d1);                               \
    d0 = fmaf(rl(h2,6), wh2_6, d0);  d1 = fmaf(rl(h2,7), wh2_7, d1);                               \
    d0 = fmaf(rl(h2,8), wh2_8, d0);  d1 = fmaf(rl(h2,9), wh2_9, d1);                               \
    const float g2  = d0 + d1;                                                                     \
    const float sg2 = sigf(g2 * zM);                                                               \
    const float act2 = fmaf(aA, sg2, aB);                                                          \
    const float ai2 = __shfl(act2, u,      64);                                                    \
    const float af2 = __shfl(act2, u + 10, 64);                                                    \
    const float ag2 = __shfl(act2, u + 20, 64);                                                    \
    const float ao2 = __shfl(act2, u + 30, 64);                                                    \
    c2 = fmaf(af2, c2, ai2 * ag2);                                                                 \
    h2 = ao2 * tanh_f(c2);                                                                         \
}while(0)

#define LAYER1(YV) do{                                                                             \
    float e0 = b1, e1 = 0.f;                                                                       \
    e0 = fmaf(rl(YV,0),  wi0,  e0);  e1 = fmaf(rl(YV,1),  wi1,  e1);                               \
    e0 = fmaf(rl(YV,2),  wi2,  e0);  e1 = fmaf(rl(YV,3),  wi3,  e1);                               \
    e0 = fmaf(rl(YV,4),  wi4,  e0);  e1 = fmaf(rl(YV,5),  wi5,  e1);                               \
    e0 = fmaf(rl(YV,6),  wi6,  e0);  e1 = fmaf(rl(YV,7),  wi7,  e1);                               \
    e0 = fmaf(rl(YV,8),  wi8,  e0);  e1 = fmaf(rl(YV,9),  wi9,  e1);                               \
    e0 = fmaf(rl(YV,10), wi10, e0);  e1 = fmaf(rl(YV,11), wi11, e1);                               \
    e0 = fmaf(rl(YV,12), wi12, e0);  e1 = fmaf(rl(YV,13), wi13, e1);                               \
    e0 = fmaf(rl(YV,14), wi14, e0);  e1 = fmaf(rl(YV,15), wi15, e1);                               \
    e0 = fmaf(hs0, wh1_0, e0);  e1 = fmaf(hs1, wh1_1, e1);                                         \
    e0 = fmaf(hs2, wh1_2, e0);  e1 = fmaf(hs3, wh1_3, e1);                                         \
    e0 = fmaf(hs4, wh1_4, e0);  e1 = fmaf(hs5, wh1_5, e1);                                         \
    e0 = fmaf(hs6, wh1_6, e0);  e1 = fmaf(hs7, wh1_7, e1);                                         \
    e0 = fmaf(hs8, wh1_8, e0);  e1 = fmaf(hs9, wh1_9, e1);                                         \
    const float g1  = e0 + e1;                                                                     \
    const float sg1 = sigf(g1 * zM);                                                               \
    const float act1 = fmaf(aA, sg1, aB);                                                          \
    const float ai1 = __shfl(act1, u,      64);                                                    \
    const float af1 = __shfl(act1, u + 10, 64);                                                    \
    const float ag1 = __shfl(act1, u + 20, 64);                                                    \
    const float ao1 = __shfl(act1, u + 30, 64);                                                    \
    c1 = fmaf(af1, c1, ai1 * ag1);                                                                 \
    h1n = ao1 * tanh_f(c1);                                                                        \
}while(0)

// NOTE: launch_bounds (64,1) — the (64,2) hint empirically drove the register
// allocator to a ~48-VGPR target, spilling all pinned weights to scratch
// (R5/R7: VGPR=48; R1 with (64,1): VGPR=92). With (64,1) the allocator may use
// up to 512; anything <=256 still runs 2 waves/SIMD at runtime (we have 2048
// waves total = 2/SIMD), so no real occupancy is lost.
__global__ __launch_bounds__(64, 1)
void lstm_fused(const float* __restrict__ x,
                const float* __restrict__ conv_w, const float* __restrict__ conv_b,
                const float* __restrict__ w_ih1,  const float* __restrict__ w_hh1,
                const float* __restrict__ b_ih1,  const float* __restrict__ b_hh1,
                const float* __restrict__ w_ih2,  const float* __restrict__ w_hh2,
                const float* __restrict__ b_ih2,  const float* __restrict__ b_hh2,
                const float* __restrict__ lin_w,  const float* __restrict__ lin_b,
                float* __restrict__ out)
{
    const int lane  = threadIdx.x;
    const int batch = blockIdx.x;
    const int grow  = (lane < G4) ? lane : (G4-1);
    const int q     = grow / 10;
    const int u     = grow - q * 10;
    const int ch    = lane & 15;
    const bool isG  = (q == 2);
    float zM = isG ? 2.f : 1.f;      // tanh(z) = 2*sig(2z)-1
    float aA = isG ? 2.f : 1.f;
    float aB = isG ? -1.f : 0.f;
    PIN(zM); PIN(aA); PIN(aB);

    // ---- loop-invariant weights: named scalars, pinned into VGPRs ----
    const float* cwp = conv_w + ch*24;
    float cw0=cwp[0],  cw1=cwp[1],  cw2=cwp[2],  cw3=cwp[3],  cw4=cwp[4],  cw5=cwp[5];
    float cw6=cwp[6],  cw7=cwp[7],  cw8=cwp[8],  cw9=cwp[9],  cw10=cwp[10],cw11=cwp[11];
    float cw12=cwp[12],cw13=cwp[13],cw14=cwp[14],cw15=cwp[15],cw16=cwp[16],cw17=cwp[17];
    float cw18=cwp[18],cw19=cwp[19],cw20=cwp[20],cw21=cwp[21],cw22=cwp[22],cw23=cwp[23];
    PIN(cw0);PIN(cw1);PIN(cw2);PIN(cw3);PIN(cw4);PIN(cw5);PIN(cw6);PIN(cw7);
    PIN(cw8);PIN(cw9);PIN(cw10);PIN(cw11);PIN(cw12);PIN(cw13);PIN(cw14);PIN(cw15);
    PIN(cw16);PIN(cw17);PIN(cw18);PIN(cw19);PIN(cw20);PIN(cw21);PIN(cw22);PIN(cw23);
    float cb = conv_b[ch]; PIN(cb);

    const float* wip = w_ih1 + grow*CC;
    float wi0=wip[0],  wi1=wip[1],  wi2=wip[2],  wi3=wip[3];
    float wi4=wip[4],  wi5=wip[5],  wi6=wip[6],  wi7=wip[7];
    float wi8=wip[8],  wi9=wip[9],  wi10=wip[10],wi11=wip[11];
    float wi12=wip[12],wi13=wip[13],wi14=wip[14],wi15=wip[15];
    PIN(wi0);PIN(wi1);PIN(wi2);PIN(wi3);PIN(wi4);PIN(wi5);PIN(wi6);PIN(wi7);
    PIN(wi8);PIN(wi9);PIN(wi10);PIN(wi11);PIN(wi12);PIN(wi13);PIN(wi14);PIN(wi15);

    const float* p1 = w_hh1 + grow*HH;
    float wh1_0=p1[0],wh1_1=p1[1],wh1_2=p1[2],wh1_3=p1[3],wh1_4=p1[4];
    float wh1_5=p1[5],wh1_6=p1[6],wh1_7=p1[7],wh1_8=p1[8],wh1_9=p1[9];
    PIN(wh1_0);PIN(wh1_1);PIN(wh1_2);PIN(wh1_3);PIN(wh1_4);
    PIN(wh1_5);PIN(wh1_6);PIN(wh1_7);PIN(wh1_8);PIN(wh1_9);

    const float* p2 = w_ih2 + grow*HH;
    float wi2_0=p2[0],wi2_1=p2[1],wi2_2=p2[2],wi2_3=p2[3],wi2_4=p2[4];
    float wi2_5=p2[5],wi2_6=p2[6],wi2_7=p2[7],wi2_8=p2[8],wi2_9=p2[9];
    PIN(wi2_0);PIN(wi2_1);PIN(wi2_2);PIN(wi2_3);PIN(wi2_4);
    PIN(wi2_5);PIN(wi2_6);PIN(wi2_7);PIN(wi2_8);PIN(wi2_9);

    const float* p3 = w_hh2 + grow*HH;
    float wh2_0=p3[0],wh2_1=p3[1],wh2_2=p3[2],wh2_3=p3[3],wh2_4=p3[4];
    float wh2_5=p3[5],wh2_6=p3[6],wh2_7=p3[7],wh2_8=p3[8],wh2_9=p3[9];
    PIN(wh2_0);PIN(wh2_1);PIN(wh2_2);PIN(wh2_3);PIN(wh2_4);
    PIN(wh2_5);PIN(wh2_6);PIN(wh2_7);PIN(wh2_8);PIN(wh2_9);

    float b1 = b_ih1[grow] + b_hh1[grow]; PIN(b1);
    float b2 = b_ih2[grow] + b_hh2[grow]; PIN(b2);

    const float* xb = x + (size_t)batch * (TT*FF);

    float h1 = 0.f, c1 = 0.f, h2 = 0.f, c2 = 0.f, h1n;

    // sliding conv window rows t-1, t, t+1
    float4 w0a = make_float4(0.f,0.f,0.f,0.f), w0b = w0a;
    float4 w1a = *(const float4*)(xb + 0);
    float4 w1b = *(const float4*)(xb + 4);
    float4 w2a = *(const float4*)(xb + 8);
    float4 w2b = *(const float4*)(xb + 12);

    // ---- prologue: t=0, layer1 only ----
    {
        float y0; CONV_Y(y0);
        H1BCAST;                 // h1(-1)=0
        LAYER1(y0);
        h1 = h1n;
    }
    w0a = w1a; w0b = w1b; w1a = w2a; w1b = w2b;
    w2a = *(const float4*)(xb + 16);
    w2b = *(const float4*)(xb + 20);

    // ---- main loop: iteration t does layer2(t-1) || layer1(t) ----
    #pragma unroll 3
    for (int t = 1; t < TT; ++t){
        float4 nxa = make_float4(0.f,0.f,0.f,0.f), nxb = nxa;
        if (t + 2 < TT){
            const float* p = xb + (t+2)*FF;
            nxa = *(const float4*)p;
            nxb = *(const float4*)(p + 4);
        }
        float y; CONV_Y(y);
        {
            H1BCAST;             // h1(t-1) broadcasts, shared by both layers
            LAYER2;              // h2(t-1) — chain A
            LAYER1(y);           // h1(t)   — chain B
        }
        h1 = h1n;
        w0a = w1a; w0b = w1b; w1a = w2a; w1b = w2b; w2a = nxa; w2b = nxb;
    }
    // ---- epilogue: layer2 for t=TT-1 ----
    {
        H1BCAST;
        LAYER2;
    }

    // final: sigmoid(h2 . lin_w + lin_b); lanes 0..9 hold h2[0..9]
    float part = (lane < HH) ? h2 * lin_w[grow] : 0.f;
    #pragma unroll
    for (int off = 8; off > 0; off >>= 1) part += __shfl_xor(part, off, 16);
    if (lane == 0) out[batch] = sigf(part + lin_b[0]);
}

extern "C" void kernel_launch(void* const* d_in, const int* in_sizes, int n_in,
                              void* d_out, int out_size, void* d_ws, size_t ws_size,
                              hipStream_t stream) {
    const float* x      = (const float*)d_in[0];
    const float* conv_w = (const float*)d_in[1];
    const float* conv_b = (const float*)d_in[2];
    const float* w_ih1  = (const float*)d_in[3];
    const float* w_hh1  = (const float*)d_in[4];
    const float* b_ih1  = (const float*)d_in[5];
    const float* b_hh1  = (const float*)d_in[6];
    const float* w_ih2  = (const float*)d_in[7];
    const float* w_hh2  = (const float*)d_in[8];
    const float* b_ih2  = (const float*)d_in[9];
    const float* b_hh2  = (const float*)d_in[10];
    const float* lin_w  = (const float*)d_in[11];
    const float* lin_b  = (const float*)d_in[12];
    float* out = (float*)d_out;

    // one wave per batch: 2048 waves -> 2 per SIMD chip-wide
    lstm_fused<<<dim3(2048), dim3(64), 0, stream>>>(
        x, conv_w, conv_b, w_ih1, w_hh1, b_ih1, b_hh1,
        w_ih2, w_hh2, b_ih2, b_hh2, lin_w, lin_b, out);
}

// Round 9
// 271.219 us; speedup vs baseline: 1.0488x; 1.0488x over previous
//
#include <hip/hip_runtime.h>

#define TT 512
#define FF 8
#define CC 16
#define HH 10
#define G4 40

__device__ __forceinline__ float rl(float v, int k){
    return __int_as_float(__builtin_amdgcn_readlane(__float_as_int(v), k));
}
__device__ __forceinline__ float sigf(float z){
    return __builtin_amdgcn_rcpf(1.f + __expf(-z));
}
__device__ __forceinline__ float tanh_f(float z){
    return 1.f - 2.f * __builtin_amdgcn_rcpf(1.f + __expf(2.f * z));
}
#define PIN(v) asm volatile("" : "+v"(v))

#define CONV_Y(Y) do{                                                                              \
    float a0 = cb, a1 = 0.f;                                                                       \
    a0 = fmaf(w0a.x, cw0,  a0); a1 = fmaf(w1a.x, cw1,  a1); a0 = fmaf(w2a.x, cw2,  a0);            \
    a1 = fmaf(w0a.y, cw3,  a1); a0 = fmaf(w1a.y, cw4,  a0); a1 = fmaf(w2a.y, cw5,  a1);            \
    a0 = fmaf(w0a.z, cw6,  a0); a1 = fmaf(w1a.z, cw7,  a1); a0 = fmaf(w2a.z, cw8,  a0);            \
    a1 = fmaf(w0a.w, cw9,  a1); a0 = fmaf(w1a.w, cw10, a0); a1 = fmaf(w2a.w, cw11, a1);            \
    a0 = fmaf(w0b.x, cw12, a0); a1 = fmaf(w1b.x, cw13, a1); a0 = fmaf(w2b.x, cw14, a0);            \
    a1 = fmaf(w0b.y, cw15, a1); a0 = fmaf(w1b.y, cw16, a0); a1 = fmaf(w2b.y, cw17, a1);            \
    a0 = fmaf(w0b.z, cw18, a0); a1 = fmaf(w1b.z, cw19, a1); a0 = fmaf(w2b.z, cw20, a0);            \
    a1 = fmaf(w0b.w, cw21, a1); a0 = fmaf(w1b.w, cw22, a0); a1 = fmaf(w2b.w, cw23, a1);            \
    Y = fmaxf(a0 + a1, 0.f);                                                                       \
}while(0)

#define H1BCAST                                                                                    \
    const float hs0=rl(h1,0), hs1=rl(h1,1), hs2=rl(h1,2), hs3=rl(h1,3), hs4=rl(h1,4),              \
                hs5=rl(h1,5), hs6=rl(h1,6), hs7=rl(h1,7), hs8=rl(h1,8), hs9=rl(h1,9);

#define LAYER2 do{                                                                                 \
    float d0 = b2, d1 = 0.f;                                                                       \
    d0 = fmaf(hs0, wi2_0, d0);  d1 = fmaf(hs1, wi2_1, d1);                                         \
    d0 = fmaf(hs2, wi2_2, d0);  d1 = fmaf(hs3, wi2_3, d1);                                         \
    d0 = fmaf(hs4, wi2_4, d0);  d1 = fmaf(hs5, wi2_5, d1);                                         \
    d0 = fmaf(hs6, wi2_6, d0);  d1 = fmaf(hs7, wi2_7, d1);                                         \
    d0 = fmaf(hs8, wi2_8, d0);  d1 = fmaf(hs9, wi2_9, d1);                                         \
    d0 = fmaf(rl(h2,0), wh2_0, d0);  d1 = fmaf(rl(h2,1), wh2_1, d1);                               \
    d0 = fmaf(rl(h2,2), wh2_2, d0);  d1 = fmaf(rl(h2,3), wh2_3, d1);                               \
    d0 = fmaf(rl(h2,4), wh2_4, d0);  d1 = fmaf(rl(h2,5), wh2_5, d1);                               \
    d0 = fmaf(rl(h2,6), wh2_6, d0);  d1 = fmaf(rl(h2,7), wh2_7, d1);                               \
    d0 = fmaf(rl(h2,8), wh2_8, d0);  d1 = fmaf(rl(h2,9), wh2_9, d1);                               \
    const float g2  = d0 + d1;                                                                     \
    const float sg2 = sigf(g2 * zM);                                                               \
    const float act2 = fmaf(aA, sg2, aB);                                                          \
    const float ai2 = __shfl(act2, u,      64);                                                    \
    const float af2 = __shfl(act2, u + 10, 64);                                                    \
    const float ag2 = __shfl(act2, u + 20, 64);                                                    \
    const float ao2 = __shfl(act2, u + 30, 64);                                                    \
    c2 = fmaf(af2, c2, ai2 * ag2);                                                                 \
    h2 = ao2 * tanh_f(c2);                                                                         \
}while(0)

#define LAYER1(YV) do{                                                                             \
    float e0 = b1, e1 = 0.f;                                                                       \
    e0 = fmaf(rl(YV,0),  wi0,  e0);  e1 = fmaf(rl(YV,1),  wi1,  e1);                               \
    e0 = fmaf(rl(YV,2),  wi2,  e0);  e1 = fmaf(rl(YV,3),  wi3,  e1);                               \
    e0 = fmaf(rl(YV,4),  wi4,  e0);  e1 = fmaf(rl(YV,5),  wi5,  e1);                               \
    e0 = fmaf(rl(YV,6),  wi6,  e0);  e1 = fmaf(rl(YV,7),  wi7,  e1);                               \
    e0 = fmaf(rl(YV,8),  wi8,  e0);  e1 = fmaf(rl(YV,9),  wi9,  e1);                               \
    e0 = fmaf(rl(YV,10), wi10, e0);  e1 = fmaf(rl(YV,11), wi11, e1);                               \
    e0 = fmaf(rl(YV,12), wi12, e0);  e1 = fmaf(rl(YV,13), wi13, e1);                               \
    e0 = fmaf(rl(YV,14), wi14, e0);  e1 = fmaf(rl(YV,15), wi15, e1);                               \
    e0 = fmaf(hs0, wh1_0, e0);  e1 = fmaf(hs1, wh1_1, e1);                                         \
    e0 = fmaf(hs2, wh1_2, e0);  e1 = fmaf(hs3, wh1_3, e1);                                         \
    e0 = fmaf(hs4, wh1_4, e0);  e1 = fmaf(hs5, wh1_5, e1);                                         \
    e0 = fmaf(hs6, wh1_6, e0);  e1 = fmaf(hs7, wh1_7, e1);                                         \
    e0 = fmaf(hs8, wh1_8, e0);  e1 = fmaf(hs9, wh1_9, e1);                                         \
    const float g1  = e0 + e1;                                                                     \
    const float sg1 = sigf(g1 * zM);                                                               \
    const float act1 = fmaf(aA, sg1, aB);                                                          \
    const float ai1 = __shfl(act1, u,      64);                                                    \
    const float af1 = __shfl(act1, u + 10, 64);                                                    \
    const float ag1 = __shfl(act1, u + 20, 64);                                                    \
    const float ao1 = __shfl(act1, u + 30, 64);                                                    \
    c1 = fmaf(af1, c1, ai1 * ag1);                                                                 \
    h1n = ao1 * tanh_f(c1);                                                                        \
}while(0)

// Weights are laundered through LDS: ds_read results are NOT invariant loads,
// so the register allocator cannot rematerialize them inside the loop — it
// must keep them live in VGPRs (R5-R8 all remat'd const-__restrict__ global
// loads every timestep, VGPR stuck at 48, ~2x instruction bloat per step).
__global__ __launch_bounds__(64, 1)
void lstm_fused(const float* __restrict__ x,
                const float* __restrict__ conv_w, const float* __restrict__ conv_b,
                const float* __restrict__ w_ih1,  const float* __restrict__ w_hh1,
                const float* __restrict__ b_ih1,  const float* __restrict__ b_hh1,
                const float* __restrict__ w_ih2,  const float* __restrict__ w_hh2,
                const float* __restrict__ b_ih2,  const float* __restrict__ b_hh2,
                const float* __restrict__ lin_w,  const float* __restrict__ lin_b,
                float* __restrict__ out)
{
    // 64 rows x 73 floats: stride 73 -> bank=(9j+m)%32, gcd(9,32)=1 -> 2-way = free
    __shared__ float wl[64][73];

    const int lane  = threadIdx.x;
    const int batch = blockIdx.x;
    const int grow  = (lane < G4) ? lane : (G4-1);
    const int q     = grow / 10;
    const int u     = grow - q * 10;
    const int ch    = lane & 15;
    const bool isG  = (q == 2);
    float zM = isG ? 2.f : 1.f;      // tanh(z) = 2*sig(2z)-1
    float aA = isG ? 2.f : 1.f;
    float aB = isG ? -1.f : 0.f;
    PIN(zM); PIN(aA); PIN(aB);

    // ---- stage this lane's weights into its LDS row ----
    {
        float* mr = wl[lane];
        const float* cwp = conv_w + ch*24;
        #pragma unroll
        for (int m = 0; m < 24; ++m) mr[m] = cwp[m];
        const float* wip = w_ih1 + grow*CC;
        #pragma unroll
        for (int m = 0; m < CC; ++m) mr[24+m] = wip[m];
        const float* q1 = w_hh1 + grow*HH;
        const float* q2 = w_ih2 + grow*HH;
        const float* q3 = w_hh2 + grow*HH;
        #pragma unroll
        for (int m = 0; m < HH; ++m){ mr[40+m]=q1[m]; mr[50+m]=q2[m]; mr[60+m]=q3[m]; }
        mr[70] = b_ih1[grow] + b_hh1[grow];
        mr[71] = b_ih2[grow] + b_hh2[grow];
        mr[72] = conv_b[ch];
    }
    __syncthreads();
    const float* mr = wl[lane];

    // ---- read back into named scalars (non-remat-able) and pin ----
    float cw0=mr[0],  cw1=mr[1],  cw2=mr[2],  cw3=mr[3],  cw4=mr[4],  cw5=mr[5];
    float cw6=mr[6],  cw7=mr[7],  cw8=mr[8],  cw9=mr[9],  cw10=mr[10],cw11=mr[11];
    float cw12=mr[12],cw13=mr[13],cw14=mr[14],cw15=mr[15],cw16=mr[16],cw17=mr[17];
    float cw18=mr[18],cw19=mr[19],cw20=mr[20],cw21=mr[21],cw22=mr[22],cw23=mr[23];
    PIN(cw0);PIN(cw1);PIN(cw2);PIN(cw3);PIN(cw4);PIN(cw5);PIN(cw6);PIN(cw7);
    PIN(cw8);PIN(cw9);PIN(cw10);PIN(cw11);PIN(cw12);PIN(cw13);PIN(cw14);PIN(cw15);
    PIN(cw16);PIN(cw17);PIN(cw18);PIN(cw19);PIN(cw20);PIN(cw21);PIN(cw22);PIN(cw23);

    float wi0=mr[24], wi1=mr[25], wi2=mr[26], wi3=mr[27];
    float wi4=mr[28], wi5=mr[29], wi6=mr[30], wi7=mr[31];
    float wi8=mr[32], wi9=mr[33], wi10=mr[34],wi11=mr[35];
    float wi12=mr[36],wi13=mr[37],wi14=mr[38],wi15=mr[39];
    PIN(wi0);PIN(wi1);PIN(wi2);PIN(wi3);PIN(wi4);PIN(wi5);PIN(wi6);PIN(wi7);
    PIN(wi8);PIN(wi9);PIN(wi10);PIN(wi11);PIN(wi12);PIN(wi13);PIN(wi14);PIN(wi15);

    float wh1_0=mr[40],wh1_1=mr[41],wh1_2=mr[42],wh1_3=mr[43],wh1_4=mr[44];
    float wh1_5=mr[45],wh1_6=mr[46],wh1_7=mr[47],wh1_8=mr[48],wh1_9=mr[49];
    PIN(wh1_0);PIN(wh1_1);PIN(wh1_2);PIN(wh1_3);PIN(wh1_4);
    PIN(wh1_5);PIN(wh1_6);PIN(wh1_7);PIN(wh1_8);PIN(wh1_9);

    float wi2_0=mr[50],wi2_1=mr[51],wi2_2=mr[52],wi2_3=mr[53],wi2_4=mr[54];
    float wi2_5=mr[55],wi2_6=mr[56],wi2_7=mr[57],wi2_8=mr[58],wi2_9=mr[59];
    PIN(wi2_0);PIN(wi2_1);PIN(wi2_2);PIN(wi2_3);PIN(wi2_4);
    PIN(wi2_5);PIN(wi2_6);PIN(wi2_7);PIN(wi2_8);PIN(wi2_9);

    float wh2_0=mr[60],wh2_1=mr[61],wh2_2=mr[62],wh2_3=mr[63],wh2_4=mr[64];
    float wh2_5=mr[65],wh2_6=mr[66],wh2_7=mr[67],wh2_8=mr[68],wh2_9=mr[69];
    PIN(wh2_0);PIN(wh2_1);PIN(wh2_2);PIN(wh2_3);PIN(wh2_4);
    PIN(wh2_5);PIN(wh2_6);PIN(wh2_7);PIN(wh2_8);PIN(wh2_9);

    float b1 = mr[70]; PIN(b1);
    float b2 = mr[71]; PIN(b2);
    float cb = mr[72]; PIN(cb);

    const float* xb = x + (size_t)batch * (TT*FF);

    float h1 = 0.f, c1 = 0.f, h2 = 0.f, c2 = 0.f, h1n;

    // sliding conv window rows t-1, t, t+1
    float4 w0a = make_float4(0.f,0.f,0.f,0.f), w0b = w0a;
    float4 w1a = *(const float4*)(xb + 0);
    float4 w1b = *(const float4*)(xb + 4);
    float4 w2a = *(const float4*)(xb + 8);
    float4 w2b = *(const float4*)(xb + 12);

    // ---- prologue: t=0, layer1 only ----
    {
        float y0; CONV_Y(y0);
        H1BCAST;                 // h1(-1)=0
        LAYER1(y0);
        h1 = h1n;
    }
    w0a = w1a; w0b = w1b; w1a = w2a; w1b = w2b;
    w2a = *(const float4*)(xb + 16);
    w2b = *(const float4*)(xb + 20);

    // ---- main loop: iteration t does layer2(t-1) || layer1(t) ----
    #pragma unroll 3
    for (int t = 1; t < TT; ++t){
        float4 nxa = make_float4(0.f,0.f,0.f,0.f), nxb = nxa;
        if (t + 2 < TT){
            const float* p = xb + (t+2)*FF;
            nxa = *(const float4*)p;
            nxb = *(const float4*)(p + 4);
        }
        float y; CONV_Y(y);
        {
            H1BCAST;             // h1(t-1) broadcasts, shared by both layers
            LAYER2;              // h2(t-1) — chain A
            LAYER1(y);           // h1(t)   — chain B
        }
        h1 = h1n;
        w0a = w1a; w0b = w1b; w1a = w2a; w1b = w2b; w2a = nxa; w2b = nxb;
    }
    // ---- epilogue: layer2 for t=TT-1 ----
    {
        H1BCAST;
        LAYER2;
    }

    // final: sigmoid(h2 . lin_w + lin_b); lanes 0..9 hold h2[0..9]
    float part = (lane < HH) ? h2 * lin_w[grow] : 0.f;
    #pragma unroll
    for (int off = 8; off > 0; off >>= 1) part += __shfl_xor(part, off, 16);
    if (lane == 0) out[batch] = sigf(part + lin_b[0]);
}

extern "C" void kernel_launch(void* const* d_in, const int* in_sizes, int n_in,
                              void* d_out, int out_size, void* d_ws, size_t ws_size,
                              hipStream_t stream) {
    const float* x      = (const float*)d_in[0];
    const float* conv_w = (const float*)d_in[1];
    const float* conv_b = (const float*)d_in[2];
    const float* w_ih1  = (const float*)d_in[3];
    const float* w_hh1  = (const float*)d_in[4];
    const float* b_ih1  = (const float*)d_in[5];
    const float* b_hh1  = (const float*)d_in[6];
    const float* w_ih2  = (const float*)d_in[7];
    const float* w_hh2  = (const float*)d_in[8];
    const float* b_ih2  = (const float*)d_in[9];
    const float* b_hh2  = (const float*)d_in[10];
    const float* lin_w  = (const float*)d_in[11];
    const float* lin_b  = (const float*)d_in[12];
    float* out = (float*)d_out;

    // one wave per batch: 2048 waves -> 2 per SIMD chip-wide
    lstm_fused<<<dim3(2048), dim3(64), 0, stream>>>(
        x, conv_w, conv_b, w_ih1, w_hh1, b_ih1, b_hh1,
        w_ih2, w_hh2, b_ih2, b_hh2, lin_w, lin_b, out);
}